// Round 1
// baseline (11.633 us; speedup 1.0000x reference)
//
#include <hip/hip_runtime.h>

__device__ __forceinline__ float sigf(float x) { return 1.0f / (1.0f + expf(-x)); }

__global__ __launch_bounds__(512) void net6max_kernel(
    const float* __restrict__ x,
    const float* __restrict__ W_ih_gen, const float* __restrict__ W_hh_gen,
    const float* __restrict__ b_ih_gen, const float* __restrict__ b_hh_gen,
    const float* __restrict__ h0_gen,  const float* __restrict__ c0_gen,
    const float* __restrict__ W_ih_game, const float* __restrict__ W_hh_game,
    const float* __restrict__ b_ih_game, const float* __restrict__ b_hh_game,
    const float* __restrict__ h0_game, const float* __restrict__ c0_game,
    const float* __restrict__ W1, const float* __restrict__ b1,
    const float* __restrict__ W2, const float* __restrict__ b2,
    const float* __restrict__ W3, const float* __restrict__ b3,
    float* __restrict__ out)
{
    __shared__ float xs[37];
    __shared__ float g_gen[400];    // (k=10, h=40)
    __shared__ float g2[1000];      // (o=5, k=10, h=20)
    __shared__ float hg[100];       // h_gen (k=10, j=10)
    __shared__ float hgame[250];    // h_game (o=5, k=10, j=5)
    __shared__ float in200[200];    // [x_gen_out(100) | avg(100)]
    __shared__ float h1v[50];
    __shared__ float h2v[10];

    const int tid = threadIdx.x;

    // ---- phase 0: stage input vector ----
    if (tid < 37) xs[tid] = x[tid];
    __syncthreads();

    // ---- phase A: all LSTM gate pre-activations ----
    if (tid < 400) {            // gen: g[k][h], dot length 12 + 10
        const int k = tid / 40, h = tid % 40;
        float s = b_ih_gen[tid] + b_hh_gen[tid];
        const float* wi = W_ih_gen + (k * 40 + h) * 12;
        #pragma unroll
        for (int i = 0; i < 12; ++i) s += wi[i] * xs[i];
        const float* wh = W_hh_gen + (k * 40 + h) * 10;
        const float* h0 = h0_gen + k * 10;
        #pragma unroll
        for (int j = 0; j < 10; ++j) s += wh[j] * h0[j];
        g_gen[tid] = s;
    }
    for (int e = tid; e < 1000; e += 512) {   // game: g2[o][k][h], dot length 4 + 5
        const int o = e / 200, rem = e % 200;
        const int k = rem / 20, h = rem % 20;
        float s = b_ih_game[k * 20 + h] + b_hh_game[k * 20 + h];
        const float* wi = W_ih_game + (k * 20 + h) * 4;
        const float* xi = xs + 12 + o * 5 + 1;     // xin[o][:]
        #pragma unroll
        for (int i = 0; i < 4; ++i) s += wi[i] * xi[i];
        const float* wh = W_hh_game + (k * 20 + h) * 5;
        const float* h0 = h0_game + (o * 10 + k) * 5;
        #pragma unroll
        for (int j = 0; j < 5; ++j) s += wh[j] * h0[j];
        g2[e] = s;
    }
    __syncthreads();

    // ---- phase B: gate nonlinearities (disjoint thread ranges) ----
    if (tid < 100) {            // h_gen[k][j]
        const int k = tid / 10, j = tid % 10;
        const float ig = g_gen[k*40 +      j];
        const float fg = g_gen[k*40 + 10 + j];
        const float gg = g_gen[k*40 + 20 + j];
        const float og = g_gen[k*40 + 30 + j];
        const float c  = sigf(fg) * c0_gen[tid] + sigf(ig) * tanhf(gg);
        hg[tid] = sigf(og) * tanhf(c);
    }
    if (tid >= 256 && tid < 506) {   // h_game[o][k][j]
        const int e = tid - 256;
        const int o = e / 50, rem = e % 50, k = rem / 5, j = rem % 5;
        const int base = (o * 10 + k) * 20;
        const float ig = g2[base +      j];
        const float fg = g2[base +  5 + j];
        const float gg = g2[base + 10 + j];
        const float og = g2[base + 15 + j];
        const float c  = sigf(fg) * c0_game[e] + sigf(ig) * tanhf(gg);
        hgame[e] = sigf(og) * tanhf(c);
    }
    __syncthreads();

    // ---- phase C: masked opponent average + assemble MLP input ----
    if (tid < 100) in200[tid] = hg[tid];               // x_gen_out
    if (tid >= 128 && tid < 228) {
        const int c = tid - 128;
        float cnt = 0.f, s = 0.f;
        #pragma unroll
        for (int o = 0; o < 5; ++o) {
            const float m = (truncf(xs[12 + o * 5]) == 1.0f) ? 1.0f : 0.0f;
            cnt += m;
            // feat[o][c]: first 50 = h_game[o] flat; last 50 = tile(h_game[o][9][:], 10)
            const float f = (c < 50) ? hgame[o * 50 + c]
                                     : hgame[o * 50 + 45 + (c - 50) % 5];
            s += m * f;
        }
        in200[100 + c] = (cnt > 0.f) ? (s / cnt) : 0.f;
    }
    __syncthreads();

    // ---- phase D: h1 = tanh(in200 @ W1^T + b1), 4 lanes per row ----
    if (tid < 200) {
        const int row = tid >> 2, seg = tid & 3;
        const float* w = W1 + row * 200 + seg * 50;
        const float* v = in200 + seg * 50;
        float p = 0.f;
        #pragma unroll
        for (int c = 0; c < 50; ++c) p += w[c] * v[c];
        p += __shfl_down(p, 2);   // 4-aligned groups, never cross the 64-lane wave
        p += __shfl_down(p, 1);
        if (seg == 0) h1v[row] = tanhf(p + b1[row]);
    }
    __syncthreads();

    // ---- phase E: h2 = tanh(h1 @ W2^T + b2) ----
    if (tid < 10) {
        const float* w = W2 + tid * 50;
        float s = b2[tid];
        #pragma unroll
        for (int c = 0; c < 50; ++c) s += w[c] * h1v[c];
        h2v[tid] = tanhf(s);
    }
    __syncthreads();

    // ---- phase F: out = tanh(h2 @ W3^T + b3) ----
    if (tid == 0) {
        float s = b3[0];
        #pragma unroll
        for (int c = 0; c < 10; ++c) s += W3[c] * h2v[c];
        out[0] = tanhf(s);
    }
}

extern "C" void kernel_launch(void* const* d_in, const int* in_sizes, int n_in,
                              void* d_out, int out_size, void* d_ws, size_t ws_size,
                              hipStream_t stream) {
    (void)in_sizes; (void)n_in; (void)out_size; (void)d_ws; (void)ws_size;
    net6max_kernel<<<1, 512, 0, stream>>>(
        (const float*)d_in[0],  // x
        (const float*)d_in[1],  // W_ih_gen
        (const float*)d_in[2],  // W_hh_gen
        (const float*)d_in[3],  // b_ih_gen
        (const float*)d_in[4],  // b_hh_gen
        (const float*)d_in[5],  // h0_gen
        (const float*)d_in[6],  // c0_gen
        (const float*)d_in[7],  // W_ih_game
        (const float*)d_in[8],  // W_hh_game
        (const float*)d_in[9],  // b_ih_game
        (const float*)d_in[10], // b_hh_game
        (const float*)d_in[11], // h0_game
        (const float*)d_in[12], // c0_game
        (const float*)d_in[13], // W1
        (const float*)d_in[14], // b1
        (const float*)d_in[15], // W2
        (const float*)d_in[16], // b2
        (const float*)d_in[17], // W3
        (const float*)d_in[18], // b3
        (float*)d_out);
}